// Round 1
// baseline (53.658 us; speedup 1.0000x reference)
//
#include <hip/hip_runtime.h>

#define NBINS 15
#define NREP 8          // workspace replicas (one per XCD) to cut atomic contention
#define WS_FLOATS (NREP * 3 * NBINS)

// ws layout: replica r: [0..14]=count, [15..29]=correct, [30..44]=conf_sum

__global__ void ece_init(float* __restrict__ ws) {
    int t = threadIdx.x;
    if (t < WS_FLOATS) ws[t] = 0.0f;
}

__global__ __launch_bounds__(256) void ece_main(const float* __restrict__ conf,
                                                const int* __restrict__ pred,
                                                const int* __restrict__ lab,
                                                float* __restrict__ ws,
                                                int nvec) {
    // Per-thread register accumulators, compile-time-indexed only (avoid scratch).
    float    acc_conf[NBINS];
    unsigned acc_pk[NBINS];   // (count<<16) | correct ; per-block sums stay < 2^16
#pragma unroll
    for (int k = 0; k < NBINS; ++k) { acc_conf[k] = 0.0f; acc_pk[k] = 0u; }

    const float4* c4 = (const float4*)conf;
    const int4*   p4 = (const int4*)pred;
    const int4*   l4 = (const int4*)lab;

    int tid    = blockIdx.x * blockDim.x + threadIdx.x;
    int stride = gridDim.x * blockDim.x;

    for (int i = tid; i < nvec; i += stride) {
        float4 c = c4[i];
        int4   p = p4[i];
        int4   l = l4[i];
        float cs[4] = {c.x, c.y, c.z, c.w};
        int   ps[4] = {p.x, p.y, p.z, p.w};
        int   ls[4] = {l.x, l.y, l.z, l.w};
#pragma unroll
        for (int e = 0; e < 4; ++e) {
            float cv = cs[e];
            // bin k covers (k/15, (k+1)/15]  ->  k = ceil(cv*15) - 1
            int b = (int)ceilf(cv * 15.0f) - 1;
            if (!(cv > 0.0f) || b < 0 || b >= NBINS) b = -1;  // invalid -> matches no bin
            unsigned inc = 0x10000u + (unsigned)(ps[e] == ls[e]);
#pragma unroll
            for (int k = 0; k < NBINS; ++k) {
                bool m = (b == k);
                acc_conf[k] += m ? cv  : 0.0f;
                acc_pk[k]   += m ? inc : 0u;
            }
        }
    }

    // Wave-level butterfly reduction (64 lanes).
#pragma unroll
    for (int k = 0; k < NBINS; ++k) {
        float    f = acc_conf[k];
        unsigned u = acc_pk[k];
#pragma unroll
        for (int m = 1; m < 64; m <<= 1) {
            f += __shfl_xor(f, m, 64);
            u += __shfl_xor(u, m, 64);
        }
        acc_conf[k] = f;
        acc_pk[k]   = u;
    }

    // Block-level reduction through LDS (4 waves), then 3 atomics per bin per block.
    __shared__ float    s_conf[4][NBINS];
    __shared__ unsigned s_pk[4][NBINS];
    int wave = threadIdx.x >> 6;
    int lane = threadIdx.x & 63;
    if (lane == 0) {
#pragma unroll
        for (int k = 0; k < NBINS; ++k) {
            s_conf[wave][k] = acc_conf[k];
            s_pk[wave][k]   = acc_pk[k];
        }
    }
    __syncthreads();
    if (threadIdx.x < NBINS) {
        int k = threadIdx.x;
        float    f = s_conf[0][k] + s_conf[1][k] + s_conf[2][k] + s_conf[3][k];
        unsigned u = s_pk[0][k] + s_pk[1][k] + s_pk[2][k] + s_pk[3][k];
        float cnt  = (float)(u >> 16);
        float corr = (float)(u & 0xFFFFu);
        float* base = ws + (blockIdx.x % NREP) * (3 * NBINS);
        atomicAdd(base + k,             cnt);
        atomicAdd(base + NBINS + k,     corr);
        atomicAdd(base + 2 * NBINS + k, f);
    }
}

__global__ void ece_final(const float* __restrict__ ws, float* __restrict__ out,
                          float inv_n) {
    int k = threadIdx.x;
    float v = 0.0f;
    if (k < NBINS) {
        float corr = 0.0f, cf = 0.0f;
#pragma unroll
        for (int r = 0; r < NREP; ++r) {
            const float* base = ws + r * (3 * NBINS);
            corr += base[NBINS + k];
            cf   += base[2 * NBINS + k];
        }
        // |avg_conf - avg_acc| * count/N == |conf_sum - correct| / N ; empty bin -> 0
        v = fabsf(cf - corr) * inv_n;
    }
#pragma unroll
    for (int m = 1; m < 64; m <<= 1) v += __shfl_xor(v, m, 64);
    if (k == 0) out[0] = v;
}

extern "C" void kernel_launch(void* const* d_in, const int* in_sizes, int n_in,
                              void* d_out, int out_size, void* d_ws, size_t ws_size,
                              hipStream_t stream) {
    const float* conf = (const float*)d_in[0];
    const int*   pred = (const int*)d_in[1];
    const int*   lab  = (const int*)d_in[2];
    float* ws  = (float*)d_ws;
    float* out = (float*)d_out;
    int n    = in_sizes[0];
    int nvec = n / 4;  // N = 16777216 is divisible by 4

    ece_init<<<1, 384, 0, stream>>>(ws);
    ece_main<<<2048, 256, 0, stream>>>(conf, pred, lab, ws, nvec);
    ece_final<<<1, 64, 0, stream>>>(ws, out, 1.0f / (float)n);
}